// Round 1
// 418.680 us; speedup vs baseline: 1.0573x; 1.0573x over previous
//
#include <hip/hip_runtime.h>
#include <cstdint>
#include <cstddef>

#define NN 207      // nodes
#define NE 1722     // edges
#define NT 24       // time buckets
#define LL 2048     // L
#define LCC 128     // columns per block (wave owns 16)
#define KP  224     // padded K (7*32)
#define KS  228     // xT LDS row stride in elements (odd*4 -> conflict-free b64 frag reads)
#define MTILES 13   // 13*16 = 208 >= 207
#define KTILES 7    // 7*32 = 224

// ws layout (bytes):
// cb4   @ 0       : float4[NT*NN] {c_r, c_ra, c_d+c_da, 0}        (79488 B)
// bb4   @ 79488   : float4[NT*NN] {b_r, b_ra, b_d+b_da, 0}        (79488 B)
// Wpack @ 158976  : f16 MFMA-A-fragment-packed dense weights
//                   chunk index ((t*13+mt)*3+mat)*7+ks, 1024 B/chunk (lane*16B)
//                   total 24*273*1024 = 6709248 B  -> ws end ~6.9 MB

typedef float   f32x4 __attribute__((ext_vector_type(4)));
typedef _Float16 half8 __attribute__((ext_vector_type(8)));

__device__ __forceinline__ unsigned short f2h(float f) {
    return __builtin_bit_cast(unsigned short, (_Float16)f);
}
__device__ __forceinline__ float tanhfast(float z) {
    return 1.0f - __fdividef(2.0f, __expf(2.0f * z) + 1.0f);
}

// K1: per (t, 16-row tile): build dense rows of the 3 matrices in LDS (f32),
// compute diag/colsum + bias tables, emit f16 fragments pre-packed in MFMA A order.
// W_R = -Ar, W_RA = +Ara, W_D = Ada - Ad  (diagonals applied in f32 epilogue of K2).
__global__ void k_build(const int* __restrict__ efrom, const int* __restrict__ eto,
                        const float* __restrict__ wr, const float* __restrict__ wd,
                        const float* __restrict__ wra, const float* __restrict__ wda,
                        const float* __restrict__ br, const float* __restrict__ bd,
                        const float* __restrict__ bra, const float* __restrict__ bda,
                        unsigned short* __restrict__ Wpack,
                        float4* __restrict__ cb4, float4* __restrict__ bb4) {
    const int t   = blockIdx.x / MTILES;
    const int mt  = blockIdx.x % MTILES;
    const int tid = threadIdx.x;              // 256
    __shared__ float rowbuf[3][16][KP];       // 43008 B
    __shared__ float cs[4][16];               // c_r, c_ra, c_d, c_da per row

    float* rb = &rowbuf[0][0][0];
    for (int i = tid; i < 3 * 16 * KP; i += 256) rb[i] = 0.0f;
    if (tid < 64) ((float*)cs)[tid] = 0.0f;
    __syncthreads();

    const int mt16 = mt * 16;
    const float* wrt  = wr  + (size_t)t * NE;
    const float* wdt  = wd  + (size_t)t * NE;
    const float* wrat = wra + (size_t)t * NE;
    const float* wdat = wda + (size_t)t * NE;
    for (int e = tid; e < NE; e += 256) {
        int ef = efrom[e], et = eto[e];
        unsigned rf = (unsigned)(ef - mt16), rt = (unsigned)(et - mt16);
        bool in_f = rf < 16u, in_t = rt < 16u;
        if (in_f || in_t) {
            float w1 = wrt[e], w2 = wdt[e], w3 = wrat[e], w4 = wdat[e];
            if (in_t) {                       // Ar/Ara colsums; Ad/Ada live at [to][from]
                atomicAdd(&rowbuf[2][rt][ef], w4 - w2);
                atomicAdd(&cs[0][rt], w1);
                atomicAdd(&cs[1][rt], w3);
            }
            if (in_f) {                       // Ar/Ara live at [from][to]; Ad/Ada colsums
                atomicAdd(&rowbuf[0][rf][et], -w1);
                atomicAdd(&rowbuf[1][rf][et],  w3);
                atomicAdd(&cs[2][rf], w2);
                atomicAdd(&cs[3][rf], w4);
            }
        }
    }
    __syncthreads();

    if (tid < 16) {
        int w = mt16 + tid;
        if (w < NN) {
            cb4[t * NN + w] = make_float4(cs[0][tid], cs[1][tid], cs[2][tid] + cs[3][tid], 0.0f);
            bb4[t * NN + w] = make_float4(br[t * NN + w], bra[t * NN + w],
                                          bd[t * NN + w] + bda[t * NN + w], 0.0f);
        }
    }

    // pack A-fragments: lane l=(g,r): elems 0..3 = W[r][ks*32+4g+e], elems 4..7 = +16
    for (int fr = tid; fr < 3 * KTILES * 64; fr += 256) {
        int mat = fr / (KTILES * 64);
        int rem = fr - mat * (KTILES * 64);
        int ks = rem >> 6, l = rem & 63;
        int r = l & 15, g = l >> 4;
        const float* src = &rowbuf[mat][r][0];
        unsigned short h[8];
        #pragma unroll
        for (int e2 = 0; e2 < 4; ++e2) h[e2]     = f2h(src[ks * 32 + 4 * g + e2]);
        #pragma unroll
        for (int e2 = 0; e2 < 4; ++e2) h[4 + e2] = f2h(src[ks * 32 + 16 + 4 * g + e2]);
        uint4 pv;
        pv.x = (unsigned)h[0] | ((unsigned)h[1] << 16);
        pv.y = (unsigned)h[2] | ((unsigned)h[3] << 16);
        pv.z = (unsigned)h[4] | ((unsigned)h[5] << 16);
        pv.w = (unsigned)h[6] | ((unsigned)h[7] << 16);
        size_t o = ((size_t)(((t * MTILES + mt) * 3 + mat) * KTILES + ks) * 64 + l) * 8;
        *(uint4*)(Wpack + o) = pv;
    }
}

// K2: MFMA main. Block (chunk, b): 512 thr = 8 waves, wave wv owns 16 cols.
// x chunk staged transposed f16 in LDS; B-fragments register-resident (7 x half8);
// A streamed linearly from packed global (1 dwordx4 per MFMA, L1/L2-hot);
// no barriers inside the K loop. Epilogue: diag + bias + tanh in f32, exact-x residual.
__global__ __launch_bounds__(512, 4) void k_mfma(
    const float* __restrict__ inputs, const int* __restrict__ ind,
    const unsigned short* __restrict__ Wpack,
    const float4* __restrict__ cb4, const float4* __restrict__ bb4,
    float* __restrict__ out) {
    __shared__ unsigned short xT[LCC * KS];   // 58368 B, xT[col][k]
    __shared__ float4 lcb[NN], lbb[NN];       // 6624 B -> total 64992 B = 2 blocks/CU
    const int b = blockIdx.y, chunk = blockIdx.x, tid = threadIdx.x;
    const int t = ind[b] / 12;

    for (int i = tid; i < NN; i += 512) { lcb[i] = cb4[t * NN + i]; lbb[i] = bb4[t * NN + i]; }
    {   // zero xT (covers K-pad rows 207..227)
        int4 z = make_int4(0, 0, 0, 0);
        for (int i = tid; i < LCC * KS * 2 / 16; i += 512) ((int4*)xT)[i] = z;
    }
    __syncthreads();

    const float* xb = inputs + (size_t)b * (2 * NN * LL) + (size_t)chunk * LCC;
    for (int i = tid; i < NN * (LCC / 4); i += 512) {
        int k = i >> 5;                        // 0..206
        int c4 = (i & 31) << 2;                // 0..124
        float4 v = *(const float4*)(xb + (size_t)k * LL + c4);
        xT[(c4 + 0) * KS + k] = f2h(v.x);
        xT[(c4 + 1) * KS + k] = f2h(v.y);
        xT[(c4 + 2) * KS + k] = f2h(v.z);
        xT[(c4 + 3) * KS + k] = f2h(v.w);
    }
    __syncthreads();

    const int l  = tid & 63, wv = tid >> 6;
    const int r  = l & 15,  g  = l >> 4;
    const int col = wv * 16 + r;               // 0..127

    // B fragments: B[k][col] = xT[col][k]; elems 0..3 = k 4g+e, 4..7 = +16
    half8 bf[KTILES];
    #pragma unroll
    for (int ks = 0; ks < KTILES; ++ks) {
        uint2 lo = *(const uint2*)&xT[col * KS + ks * 32 + 4 * g];
        uint2 hi = *(const uint2*)&xT[col * KS + ks * 32 + 16 + 4 * g];
        uint4 u; u.x = lo.x; u.y = lo.y; u.z = hi.x; u.w = hi.y;
        bf[ks] = __builtin_bit_cast(half8, u);
    }

    const unsigned short* Ap = Wpack + (size_t)t * (MTILES * 3 * KTILES * 512) + (size_t)l * 8;
    const float* xrd = inputs + (size_t)b * (2 * NN * LL) + (size_t)chunk * LCC + col;
    float* ob = out + (size_t)b * ((size_t)NN * LL) + (size_t)chunk * LCC + col;

    for (int mt = 0; mt < MTILES; ++mt) {
        f32x4 aR = {0.f, 0.f, 0.f, 0.f};
        f32x4 aA = {0.f, 0.f, 0.f, 0.f};
        f32x4 aD = {0.f, 0.f, 0.f, 0.f};
        #pragma unroll
        for (int ks = 0; ks < KTILES; ++ks) {
            half8 a = __builtin_bit_cast(half8, *(const uint4*)Ap); Ap += 512;
            aR = __builtin_amdgcn_mfma_f32_16x16x32_f16(a, bf[ks], aR, 0, 0, 0);
        }
        #pragma unroll
        for (int ks = 0; ks < KTILES; ++ks) {
            half8 a = __builtin_bit_cast(half8, *(const uint4*)Ap); Ap += 512;
            aA = __builtin_amdgcn_mfma_f32_16x16x32_f16(a, bf[ks], aA, 0, 0, 0);
        }
        #pragma unroll
        for (int ks = 0; ks < KTILES; ++ks) {
            half8 a = __builtin_bit_cast(half8, *(const uint4*)Ap); Ap += 512;
            aD = __builtin_amdgcn_mfma_f32_16x16x32_f16(a, bf[ks], aD, 0, 0, 0);
        }
        const int rowb = mt * 16 + 4 * g;      // D row = 4g+q (verified C/D layout)
        #pragma unroll
        for (int q = 0; q < 4; ++q) {
            int row = rowb + q;
            if (row < NN) {
                float xq = xrd[(size_t)row * LL];          // exact f32 x
                float4 cb = lcb[row], bb = lbb[row];
                float rr = aR[q] + cb.x * xq + bb.x;
                float ra = aA[q] + bb.y;
                if (b != 0) ra += cb.y * xq;               // colsum(RW[0]) == 0 analytically
                float dd = aD[q] + cb.z * xq + bb.z;
                ob[(size_t)row * LL] = tanhfast(rr) + tanhfast(ra) + dd + xq;
            }
        }
    }
}

extern "C" void kernel_launch(void* const* d_in, const int* in_sizes, int n_in,
                              void* d_out, int out_size, void* d_ws, size_t ws_size,
                              hipStream_t stream) {
    const float* inputs = (const float*)d_in[0];
    const int*   ind    = (const int*)d_in[1];
    const int*   efrom  = (const int*)d_in[2];
    const int*   eto    = (const int*)d_in[3];
    const float* wr     = (const float*)d_in[4];
    const float* wd     = (const float*)d_in[5];
    const float* wra    = (const float*)d_in[6];
    const float* wda    = (const float*)d_in[7];
    const float* br     = (const float*)d_in[8];
    const float* bd     = (const float*)d_in[9];
    const float* bra    = (const float*)d_in[10];
    const float* bda    = (const float*)d_in[11];
    float* out = (float*)d_out;

    char* ws = (char*)d_ws;
    float4*         cb4   = (float4*)(ws + 0);
    float4*         bb4   = (float4*)(ws + 79488);
    unsigned short* Wpack = (unsigned short*)(ws + 158976);

    const int B = in_sizes[1];   // 64

    k_build<<<dim3(NT * MTILES), dim3(256), 0, stream>>>(
        efrom, eto, wr, wd, wra, wda, br, bd, bra, bda, Wpack, cb4, bb4);
    k_mfma<<<dim3(LL / LCC, B), dim3(512), 0, stream>>>(
        inputs, ind, Wpack, cb4, bb4, out);
}